// Round 9
// baseline (255.639 us; speedup 1.0000x reference)
//
#include <hip/hip_runtime.h>
#include <hip/hip_bf16.h>

#define CCH 64
#define KOFF 27
#define EPSV 1e-5f

typedef short bf16x8 __attribute__((ext_vector_type(8)));
typedef float f32x4  __attribute__((ext_vector_type(4)));

__device__ __forceinline__ void gld16(const void* g, void* l) {
    __builtin_amdgcn_global_load_lds((const __attribute__((address_space(1))) void*)g,
                                     (__attribute__((address_space(3))) void*)l, 16, 0, 0);
}

// --- fused pre-pass: blocks [0,54) pack W images; blocks [54,..) do stats(x).
// W[k][c][d] fp32 -> fragment-order bf16 image (layout validated r7):
// elem e: p=e>>3, j=e&7; p=((n*2+half)*4+chunk)*16+col16;
// value = W[k][c=chunk*8+half*32+j][d=n*16+col16]
__global__ __launch_bounds__(256) void k_pre(const float* __restrict__ W1,
                                             const float* __restrict__ W2,
                                             __hip_bfloat16* __restrict__ img1,
                                             __hip_bfloat16* __restrict__ img2,
                                             const float* __restrict__ x, int N,
                                             float* __restrict__ sum,
                                             float* __restrict__ sumsq) {
    if (blockIdx.x < 2 * KOFF) {
        int k = blockIdx.x;
        const float* W = W1; __hip_bfloat16* img = img1;
        if (k >= KOFF) { k -= KOFF; W = W2; img = img2; }
        const float* src = W + (size_t)k * CCH * CCH;
        __hip_bfloat16* dst = img + (size_t)k * CCH * CCH;
        for (int e = threadIdx.x; e < CCH * CCH; e += 256) {
            const int p = e >> 3, j = e & 7;
            const int n = p >> 7, half = (p >> 6) & 1, chunk = (p >> 4) & 3, col = p & 15;
            dst[e] = __float2bfloat16(src[(chunk * 8 + half * 32 + j) * CCH + n * 16 + col]);
        }
        return;
    }
    // ---- stats over x: float4 loads, 16 rows x 16 channel-groups per block
    const int bid = blockIdx.x - 2 * KOFF;
    const int nb  = gridDim.x - 2 * KOFF;
    const int c4  = threadIdx.x & 15;       // channel group (4 ch)
    const int rg  = threadIdx.x >> 4;       // 0..15 row group
    f32x4 s = {0.f, 0.f, 0.f, 0.f}, s2 = {0.f, 0.f, 0.f, 0.f};
    for (int r = bid * 16 + rg; r < N; r += nb * 16) {
        const float4 v = ((const float4*)x)[(size_t)r * 16 + c4];
        s[0] += v.x; s[1] += v.y; s[2] += v.z; s[3] += v.w;
        s2[0] += v.x * v.x; s2[1] += v.y * v.y; s2[2] += v.z * v.z; s2[3] += v.w * v.w;
    }
    __shared__ float sh[2][16][64];         // 8 KB
#pragma unroll
    for (int j = 0; j < 4; ++j) {
        sh[0][rg][c4 * 4 + j] = s[j];
        sh[1][rg][c4 * 4 + j] = s2[j];
    }
    __syncthreads();
    if (threadIdx.x < 128) {
        const int which = threadIdx.x >> 6;   // 0=sum 1=sumsq
        const int c     = threadIdx.x & 63;
        float a = 0.f;
#pragma unroll
        for (int g = 0; g < 16; ++g) a += sh[which][g][c];
        atomicAdd(which ? &sumsq[c] : &sum[c], a);
    }
}

// ---------------- BN (training stats) + ReLU -> bf16 rows, zero pad row N
__global__ __launch_bounds__(256) void k_bnrelu_bf16(const float* __restrict__ x,
                                                     const float* __restrict__ sum,
                                                     const float* __restrict__ sumsq,
                                                     const float* __restrict__ gamma,
                                                     const float* __restrict__ beta,
                                                     __hip_bfloat16* __restrict__ h,
                                                     int N) {
    const float invN = 1.0f / (float)N;
    const int total = (N + 1) * 8;            // groups of 8 channels (16B bf16)
    for (int i = blockIdx.x * 256 + threadIdx.x; i < total; i += gridDim.x * 256) {
        const int r  = i >> 3;
        const int c0 = (i & 7) * 8;
        union { __hip_bfloat16 b[8]; int4 v; } pk;
        if (r < N) {
            const float4 va = ((const float4*)x)[i * 2];
            const float4 vb = ((const float4*)x)[i * 2 + 1];
            const float vv[8] = {va.x, va.y, va.z, va.w, vb.x, vb.y, vb.z, vb.w};
#pragma unroll
            for (int j = 0; j < 8; ++j) {
                const int c     = c0 + j;
                const float m   = sum[c] * invN;
                const float var = sumsq[c] * invN - m * m;
                const float sc  = gamma[c] * rsqrtf(var + EPSV);
                const float sh_ = beta[c] - m * sc;
                float t = vv[j] * sc + sh_;
                t = t > 0.0f ? t : 0.0f;
                pk.b[j] = __float2bfloat16(t);
            }
        } else {
            pk.v = make_int4(0, 0, 0, 0);     // zero pad row for kmap misses
        }
        ((int4*)h)[i] = pk.v;
    }
}

// ------------------------------------------ MFMA gather-conv, 64 pts/block.
// 4 waves x 16 points; grid ~1563 -> ~6 blocks/CU (LDS 23KB), occupancy ~70%.
// Per k: W-slice double-buffered in LDS (linear gld16, conflict-free b128
// reads); kmap slab in LDS; A gathered from global, prefetched 1 iter ahead.
// Optional fused per-channel sum/sumsq of the conv output (for the next BN).
__global__ __launch_bounds__(256) void k_conv_mfma(const __hip_bfloat16* __restrict__ h,
                                                   const int* __restrict__ kmap,
                                                   const __hip_bfloat16* __restrict__ Wimg,
                                                   const float* __restrict__ resid,
                                                   float* __restrict__ out, int N,
                                                   float* __restrict__ stat_sum,
                                                   float* __restrict__ stat_sq) {
    __shared__ int sidx[64 * KOFF];               // 6912 B
    __shared__ __hip_bfloat16 wbuf[2][4096];      // 2 x 8 KB
    __shared__ float st[2][64];                   // fused-stats reduce

    const int t     = threadIdx.x;
    const int lane  = t & 63;
    const int wave  = t >> 6;
    const int col16 = lane & 15;
    const int chunk = lane >> 4;
    const int base  = blockIdx.x * 64;
    const int p0    = base + wave * 16;

    // kmap slab, coalesced; rows >= N -> idx = N (zero row)
    const long gbase = (long)base * KOFF;
    const long glim  = (long)N * KOFF;
    for (int j = t; j < 64 * KOFF; j += 256)
        sidx[j] = (gbase + j < glim) ? kmap[gbase + j] : N;

    // stage W-slice k=0 (linear: lane x 16B)
    {
        const __hip_bfloat16* g = Wimg + t * 8;
        gld16(g,        &wbuf[0][t * 8]);
        gld16(g + 2048, &wbuf[0][t * 8 + 2048]);
    }
    __syncthreads();   // slab + buf0 ready

    const int r0 = wave * 16 + col16;   // local row of this lane's A-frag

    f32x4  acc[4] = {};
    bf16x8 a0p, a1p;

    // prefetch A(k=0)
    {
        const int i0 = sidx[r0 * KOFF];
        const bf16x8* A0 = (const bf16x8*)(h + (size_t)i0 * CCH) + chunk;
        a0p = A0[0]; a1p = A0[4];
    }

    for (int k = 0; k < KOFF; ++k) {
        if (k + 1 < KOFF) {   // stage next W-slice (buffer freed by prev barrier)
            const __hip_bfloat16* g = Wimg + (size_t)(k + 1) * 4096 + t * 8;
            const int nb = (k + 1) & 1;
            gld16(g,        &wbuf[nb][t * 8]);
            gld16(g + 2048, &wbuf[nb][t * 8 + 2048]);
        }
        const bf16x8 a0 = a0p, a1 = a1p;
        if (k + 1 < KOFF) {   // prefetch A(k+1)
            const int i0 = sidx[r0 * KOFF + k + 1];
            const bf16x8* A0 = (const bf16x8*)(h + (size_t)i0 * CCH) + chunk;
            a0p = A0[0]; a1p = A0[4];
        }
        const bf16x8* bp = (const bf16x8*)&wbuf[k & 1][0] + lane;
#pragma unroll
        for (int n = 0; n < 4; ++n) {
            const bf16x8 b0 = bp[(n * 2 + 0) * 64];
            const bf16x8 b1 = bp[(n * 2 + 1) * 64];
            acc[n] = __builtin_amdgcn_mfma_f32_16x16x32_bf16(a0, b0, acc[n], 0, 0, 0);
            acc[n] = __builtin_amdgcn_mfma_f32_16x16x32_bf16(a1, b1, acc[n], 0, 0, 0);
        }
        __syncthreads();  // all waves done with wbuf[k&1]; drains staging
    }

    if (stat_sum && t < 128) st[t >> 6][t & 63] = 0.0f;
    if (stat_sum) __syncthreads();

    // epilogue: D col = lane&15 (out-ch), row = chunk*4 + reg  [validated r3/r7]
#pragma unroll
    for (int n = 0; n < 4; ++n) {
        const int col = n * 16 + col16;
        float s = 0.f, s2 = 0.f;
#pragma unroll
        for (int j = 0; j < 4; ++j) {
            const int row = p0 + chunk * 4 + j;
            if (row < N) {
                float v = acc[n][j];
                if (resid) v += resid[(size_t)row * CCH + col];
                out[(size_t)row * CCH + col] = v;
                s += v; s2 += v * v;
            }
        }
        if (stat_sum) {
            atomicAdd(&st[0][col], s);
            atomicAdd(&st[1][col], s2);
        }
    }
    if (stat_sum) {
        __syncthreads();
        if (t < 64)       atomicAdd(&stat_sum[t], st[0][t]);
        else if (t < 128) atomicAdd(&stat_sq[t - 64], st[1][t - 64]);
    }
}

// ---------------------------------------------------------------- launcher
extern "C" void kernel_launch(void* const* d_in, const int* in_sizes, int n_in,
                              void* d_out, int out_size, void* d_ws, size_t ws_size,
                              hipStream_t stream) {
    const float* x      = (const float*)d_in[0];
    const int*   kmap   = (const int*)d_in[1];
    const float* gamma1 = (const float*)d_in[2];
    const float* beta1  = (const float*)d_in[3];
    const float* W1     = (const float*)d_in[4];
    const float* gamma2 = (const float*)d_in[5];
    const float* beta2  = (const float*)d_in[6];
    const float* W2     = (const float*)d_in[7];
    float*       out    = (float*)d_out;

    const int N = in_sizes[0] / CCH;  // 100000

    // ws layout: h_bf16 [(N+1)][64] | img1 | img2 | stats(256 f32)
    char* wp = (char*)d_ws;
    __hip_bfloat16* hbuf = (__hip_bfloat16*)wp;  wp += ((size_t)(N + 1) * CCH * 2 + 255) & ~255ull;
    __hip_bfloat16* img1 = (__hip_bfloat16*)wp;  wp += ((size_t)KOFF * CCH * CCH * 2 + 255) & ~255ull;
    __hip_bfloat16* img2 = (__hip_bfloat16*)wp;  wp += ((size_t)KOFF * CCH * CCH * 2 + 255) & ~255ull;
    float*          stats = (float*)wp;

    hipMemsetAsync(stats, 0, 256 * sizeof(float), stream);

    // W-image pack + stats(x), one dispatch
    k_pre<<<2 * KOFF + 512, 256, 0, stream>>>(W1, W2, img1, img2, x, N,
                                              stats + 0, stats + 64);

    const int cgrid = (N + 63) / 64;

    // --- block 1: BN1 -> ReLU -> conv(W1) -> d_out; fused stats for BN2
    k_bnrelu_bf16<<<2048, 256, 0, stream>>>(x, stats + 0, stats + 64, gamma1, beta1, hbuf, N);
    k_conv_mfma  <<<cgrid, 256, 0, stream>>>(hbuf, kmap, img1, nullptr, out, N,
                                             stats + 128, stats + 192);

    // --- block 2: BN2 -> ReLU -> conv(W2) + residual(x) -> d_out
    k_bnrelu_bf16<<<2048, 256, 0, stream>>>(out, stats + 128, stats + 192, gamma2, beta2, hbuf, N);
    k_conv_mfma  <<<cgrid, 256, 0, stream>>>(hbuf, kmap, img2, x, out, N,
                                             nullptr, nullptr);
}